// Round 1
// baseline (203.874 us; speedup 1.0000x reference)
//
#include <hip/hip_runtime.h>

#define EPSV 1e-5f

// ---------------------------------------------------------------------------
// Kernel 1: pool kctx (channels 32..63) to 7x7, apply wk conv1x1 + BN.
// Output kbuf layout: [b][o=g*8+c][l=p*7+q], B*32*49 floats.
// Grid: B*7 = 56 blocks (one per (b, pooled-row p)), 256 threads.
// ---------------------------------------------------------------------------
__global__ __launch_bounds__(256) void pool_k_kernel(
    const float* __restrict__ x,
    const float* __restrict__ wk_w, const float* __restrict__ wk_g,
    const float* __restrict__ wk_b, const float* __restrict__ wk_m,
    const float* __restrict__ wk_v, float* __restrict__ kbuf)
{
  const int b = blockIdx.x / 7;
  const int p = blockIdx.x % 7;
  const int tid = threadIdx.x;
  __shared__ float s_tmp[32 * 64];  // row-pooled [c][w]
  __shared__ float s_kp[32 * 7];    // fully pooled [c][q]

  const int sh = (p * 64) / 7, eh = ((p + 1) * 64 + 6) / 7;
  const float invH = 1.0f / (float)(eh - sh);
  for (int idx = tid; idx < 2048; idx += 256) {
    const int c = idx >> 6, ww = idx & 63;
    const float* xp = x + ((size_t)(b * 64 + 32 + c)) * 4096 + ww;
    float s = 0.f;
    for (int hh = sh; hh < eh; ++hh) s += xp[hh * 64];
    s_tmp[idx] = s * invH;
  }
  __syncthreads();
  if (tid < 224) {
    const int c = tid / 7, q = tid % 7;
    const int sw = (q * 64) / 7, ew = ((q + 1) * 64 + 6) / 7;
    float s = 0.f;
    for (int ww = sw; ww < ew; ++ww) s += s_tmp[c * 64 + ww];
    s_kp[c * 7 + q] = s / (float)(ew - sw);
  }
  __syncthreads();
  if (tid < 224) {
    const int o = tid / 7, q = tid % 7;
    float s = 0.f;
#pragma unroll
    for (int i = 0; i < 32; i++) s += wk_w[o * 32 + i] * s_kp[i * 7 + q];
    const float sc = wk_g[o] * rsqrtf(wk_v[o] + EPSV);
    kbuf[(size_t)b * 1568 + o * 49 + p * 7 + q] = (s - wk_m[o]) * sc + wk_b[o];
  }
}

// ---------------------------------------------------------------------------
// Kernel 2: fused q-proj + logits + proj + bias + softmax + na2d-AV + final
// 64x64 conv + BN.
// Grid: B*H = 512 blocks, block = 256 threads = 4 heads x 64 cols (one row).
// All weight accesses are wave-uniform -> scalar (s_load) promoted.
// ---------------------------------------------------------------------------
__global__ __launch_bounds__(256) void contmix_main(
    const float* __restrict__ x,
    const float* __restrict__ wq_w, const float* __restrict__ wq_g,
    const float* __restrict__ wq_b, const float* __restrict__ wq_m,
    const float* __restrict__ wq_v,
    const float* __restrict__ proj_w, const float* __restrict__ proj_b,
    const float* __restrict__ rpb1, const float* __restrict__ rpb2,
    const float* __restrict__ dy_w, const float* __restrict__ dy_g,
    const float* __restrict__ dy_b, const float* __restrict__ dy_m,
    const float* __restrict__ dy_v,
    const float* __restrict__ kbuf,
    float* __restrict__ out)
{
  __shared__ float s_rpb1[4 * 81];
  __shared__ float s_rpb2[4 * 169];
  __shared__ float s_val[64 * 64];  // row result [ch][w] pre-final-conv

  const int bx = blockIdx.x;
  const int b = bx >> 6;
  const int h = bx & 63;
  const int tid = threadIdx.x;
  const int g = tid >> 6;           // wave-uniform by construction
  const int w = tid & 63;
  const int gu = __builtin_amdgcn_readfirstlane(g);  // force SGPR

  for (int i = tid; i < 324; i += 256) s_rpb1[i] = rpb1[i];
  for (int i = tid; i < 676; i += 256) s_rpb2[i] = rpb2[i];
  __syncthreads();

  const float* xb = x + (size_t)b * 64 * 4096;

  // ---- q = BN(wq @ x[0:32]) * SCALE : 8 channels of this head ----
  float q8[8];
#pragma unroll
  for (int o = 0; o < 8; o++) q8[o] = 0.f;
  {
    const float* wqr = wq_w + gu * 8 * 32;  // uniform base
#pragma unroll
    for (int i = 0; i < 32; i++) {
      const float xv = xb[i * 4096 + h * 64 + w];
#pragma unroll
      for (int o = 0; o < 8; o++) q8[o] += wqr[o * 32 + i] * xv;
    }
#pragma unroll
    for (int o = 0; o < 8; o++) {
      const int oc = gu * 8 + o;
      const float s = wq_g[oc] * rsqrtf(wq_v[oc] + EPSV);
      q8[o] = (q8[o] * s + (wq_b[oc] - wq_m[oc] * s)) * 0.25f;
    }
  }

  // ---- wv[l] = q8 . k[:, l]  (49 pooled positions) ----
  float wv[49];
  {
    const float* kkb = kbuf + (size_t)b * 1568 + gu * 392;  // uniform base
#pragma unroll
    for (int l = 0; l < 49; l++) {
      float s = 0.f;
#pragma unroll
      for (int c = 0; c < 8; c++) s += q8[c] * kkb[c * 49 + l];
      wv[l] = s;
    }
  }

  // ---- relative-position-bias index bases (reference uses reversed pixel) --
  const int ph = 63 - h, pw = 63 - w;
  const int bih5 = ph - min(max(ph - 2, 0), 59);
  const int biw5 = pw - min(max(pw - 2, 0), 59);
  const int bih7 = ph - min(max(ph - 3, 0), 57);
  const int biw7 = pw - min(max(pw - 3, 0), 57);
  const int si5 = min(max(h - 2, 0), 59), sj5 = min(max(w - 2, 0), 59);
  const int si7 = min(max(h - 3, 0), 57), sj7 = min(max(w - 3, 0), 57);

  // ================= attn1 branch (5x5 = 25) =================
  {
    float l1[25];
#pragma unroll
    for (int o = 0; o < 25; o++) {
      float s = proj_b[o];
#pragma unroll
      for (int l = 0; l < 49; l++) s += proj_w[o * 49 + l] * wv[l];
      l1[o] = s;
    }
    const float* rp1 = s_rpb1 + gu * 81 + bih5 * 9 + biw5;
#pragma unroll
    for (int ki = 0; ki < 5; ki++)
#pragma unroll
      for (int kj = 0; kj < 5; kj++) l1[ki * 5 + kj] += rp1[ki * 9 + kj];

    float mx = l1[0];
#pragma unroll
    for (int o = 1; o < 25; o++) mx = fmaxf(mx, l1[o]);
    float sum = 0.f;
#pragma unroll
    for (int o = 0; o < 25; o++) {
      const float e = __expf(l1[o] - mx);
      l1[o] = e;
      sum += e;
    }
    const float inv = 1.f / sum;

    float acc[8];
#pragma unroll
    for (int c = 0; c < 8; c++) acc[c] = 0.f;
    const float* vb = xb + gu * 8 * 4096;
#pragma unroll
    for (int i = 0; i < 5; i++) {
      const float* vr = vb + (si5 + i) * 64 + sj5;
#pragma unroll
      for (int j = 0; j < 5; j++) {
        const float a = l1[i * 5 + j];
#pragma unroll
        for (int c = 0; c < 8; c++) acc[c] += a * vr[c * 4096 + j];
      }
    }
#pragma unroll
    for (int c = 0; c < 8; c++) s_val[(gu * 8 + c) * 64 + w] = acc[c] * inv;
  }

  // ================= attn2 branch (7x7 = 49) =================
  {
    float l2[49];
#pragma unroll
    for (int o = 0; o < 49; o++) {
      float s = proj_b[25 + o];
#pragma unroll
      for (int l = 0; l < 49; l++) s += proj_w[(25 + o) * 49 + l] * wv[l];
      l2[o] = s;
    }
    const float* rp2 = s_rpb2 + gu * 169 + bih7 * 13 + biw7;
#pragma unroll
    for (int ki = 0; ki < 7; ki++)
#pragma unroll
      for (int kj = 0; kj < 7; kj++) l2[ki * 7 + kj] += rp2[ki * 13 + kj];

    float mx = l2[0];
#pragma unroll
    for (int o = 1; o < 49; o++) mx = fmaxf(mx, l2[o]);
    float sum = 0.f;
#pragma unroll
    for (int o = 0; o < 49; o++) {
      const float e = __expf(l2[o] - mx);
      l2[o] = e;
      sum += e;
    }
    const float inv = 1.f / sum;

    float acc[8];
#pragma unroll
    for (int c = 0; c < 8; c++) acc[c] = 0.f;
    const float* vb = xb + (32 + gu * 8) * 4096;
#pragma unroll
    for (int i = 0; i < 7; i++) {
      const float* vr = vb + (si7 + i) * 64 + sj7;
#pragma unroll
      for (int j = 0; j < 7; j++) {
        const float a = l2[i * 7 + j];
#pragma unroll
        for (int c = 0; c < 8; c++) acc[c] += a * vr[c * 4096 + j];
      }
    }
#pragma unroll
    for (int c = 0; c < 8; c++) s_val[(32 + gu * 8 + c) * 64 + w] = acc[c] * inv;
  }

  __syncthreads();

  // ================= fused final conv1x1 (64->64) + BN =================
  // 256 threads = 4 out-channel groups of 16 x 64 cols.
  {
    float facc[16];
#pragma unroll
    for (int oo = 0; oo < 16; oo++) facc[oo] = 0.f;
    const float* dwr = dy_w + gu * 16 * 64;  // uniform base (og == g)
#pragma unroll
    for (int i = 0; i < 64; i++) {
      const float v = s_val[i * 64 + w];
#pragma unroll
      for (int oo = 0; oo < 16; oo++) facc[oo] += dwr[oo * 64 + i] * v;
    }
#pragma unroll
    for (int oo = 0; oo < 16; oo++) {
      const int oc = gu * 16 + oo;
      const float sc = dy_g[oc] * rsqrtf(dy_v[oc] + EPSV);
      out[((size_t)(b * 64 + oc)) * 4096 + h * 64 + w] =
          (facc[oo] - dy_m[oc]) * sc + dy_b[oc];
    }
  }
}

// ---------------------------------------------------------------------------
extern "C" void kernel_launch(void* const* d_in, const int* in_sizes, int n_in,
                              void* d_out, int out_size, void* d_ws, size_t ws_size,
                              hipStream_t stream)
{
  const float* x      = (const float*)d_in[0];
  const float* wq_w   = (const float*)d_in[1];
  const float* wq_g   = (const float*)d_in[2];
  const float* wq_b   = (const float*)d_in[3];
  const float* wq_m   = (const float*)d_in[4];
  const float* wq_v   = (const float*)d_in[5];
  const float* wk_w   = (const float*)d_in[6];
  const float* wk_g   = (const float*)d_in[7];
  const float* wk_b   = (const float*)d_in[8];
  const float* wk_m   = (const float*)d_in[9];
  const float* wk_v   = (const float*)d_in[10];
  const float* proj_w = (const float*)d_in[11];
  const float* proj_b = (const float*)d_in[12];
  const float* rpb1   = (const float*)d_in[13];
  const float* rpb2   = (const float*)d_in[14];
  const float* dy_w   = (const float*)d_in[15];
  const float* dy_g   = (const float*)d_in[16];
  const float* dy_b   = (const float*)d_in[17];
  const float* dy_m   = (const float*)d_in[18];
  const float* dy_v   = (const float*)d_in[19];

  float* kbuf = (float*)d_ws;  // 8*32*49 floats = 50 KB

  pool_k_kernel<<<56, 256, 0, stream>>>(x, wk_w, wk_g, wk_b, wk_m, wk_v, kbuf);
  contmix_main<<<512, 256, 0, stream>>>(x, wq_w, wq_g, wq_b, wq_m, wq_v,
                                        proj_w, proj_b, rpb1, rpb2,
                                        dy_w, dy_g, dy_b, dy_m, dy_v,
                                        kbuf, (float*)d_out);
}

// Round 2
// 196.024 us; speedup vs baseline: 1.0400x; 1.0400x over previous
//
#include <hip/hip_runtime.h>

#define EPSV 1e-5f

// ---------------------------------------------------------------------------
// Kernel 1: pool kctx (channels 32..63) to 7x7, apply wk conv1x1 + BN.
// Output kbuf layout: [b][o=g*8+c][l=p*7+q], B*32*49 floats.
// ---------------------------------------------------------------------------
__global__ __launch_bounds__(256) void pool_k_kernel(
    const float* __restrict__ x,
    const float* __restrict__ wk_w, const float* __restrict__ wk_g,
    const float* __restrict__ wk_b, const float* __restrict__ wk_m,
    const float* __restrict__ wk_v, float* __restrict__ kbuf)
{
  const int b = blockIdx.x / 7;
  const int p = blockIdx.x % 7;
  const int tid = threadIdx.x;
  __shared__ float s_tmp[32 * 64];  // row-pooled [c][w]
  __shared__ float s_kp[32 * 7];    // fully pooled [c][q]

  const int sh = (p * 64) / 7, eh = ((p + 1) * 64 + 6) / 7;
  const float invH = 1.0f / (float)(eh - sh);
  for (int idx = tid; idx < 2048; idx += 256) {
    const int c = idx >> 6, ww = idx & 63;
    const float* xp = x + ((size_t)(b * 64 + 32 + c)) * 4096 + ww;
    float s = 0.f;
    for (int hh = sh; hh < eh; ++hh) s += xp[hh * 64];
    s_tmp[idx] = s * invH;
  }
  __syncthreads();
  if (tid < 224) {
    const int c = tid / 7, q = tid % 7;
    const int sw = (q * 64) / 7, ew = ((q + 1) * 64 + 6) / 7;
    float s = 0.f;
    for (int ww = sw; ww < ew; ++ww) s += s_tmp[c * 64 + ww];
    s_kp[c * 7 + q] = s / (float)(ew - sw);
  }
  __syncthreads();
  if (tid < 224) {
    const int o = tid / 7, q = tid % 7;
    float s = 0.f;
#pragma unroll
    for (int i = 0; i < 32; i++) s += wk_w[o * 32 + i] * s_kp[i * 7 + q];
    const float sc = wk_g[o] * rsqrtf(wk_v[o] + EPSV);
    kbuf[(size_t)b * 1568 + o * 49 + p * 7 + q] = (s - wk_m[o]) * sc + wk_b[o];
  }
}

// ---------------------------------------------------------------------------
// Kernel 2: fused main. Block = 512 threads = 2 branches x 4 heads x 64 cols,
// one image row per block. Each pixel-head is handled by TWO threads (one per
// attention branch) to double occupancy and halve the serial VALU chain.
// Weight reads are wave-uniform -> scalar-promoted.
// ---------------------------------------------------------------------------
__global__ __launch_bounds__(512, 4) void contmix_main(
    const float* __restrict__ x,
    const float* __restrict__ wq_w, const float* __restrict__ wq_g,
    const float* __restrict__ wq_b, const float* __restrict__ wq_m,
    const float* __restrict__ wq_v,
    const float* __restrict__ proj_w, const float* __restrict__ proj_b,
    const float* __restrict__ rpb1, const float* __restrict__ rpb2,
    const float* __restrict__ dy_w, const float* __restrict__ dy_g,
    const float* __restrict__ dy_b, const float* __restrict__ dy_m,
    const float* __restrict__ dy_v,
    const float* __restrict__ kbuf,
    float* __restrict__ out)
{
  __shared__ float s_rpb1[4 * 81];
  __shared__ float s_rpb2[4 * 169];
  __shared__ float s_val[64 * 64];  // row result [ch][w] pre-final-conv

  const int bx = blockIdx.x;
  const int b = bx >> 6;
  const int h = bx & 63;
  const int tid = threadIdx.x;
  const int w = tid & 63;
  // branch and head are wave-uniform by construction; force to SGPRs.
  const int bru = __builtin_amdgcn_readfirstlane(tid >> 8);
  const int gu  = __builtin_amdgcn_readfirstlane((tid >> 6) & 3);

  for (int i = tid; i < 324; i += 512) s_rpb1[i] = rpb1[i];
  for (int i = tid; i < 676; i += 512) s_rpb2[i] = rpb2[i];
  __syncthreads();

  const float* xb = x + (size_t)b * 64 * 4096;

  // ---- q = BN(wq @ x[0:32]) * SCALE : 8 channels of this head ----
  float q8[8];
#pragma unroll
  for (int o = 0; o < 8; o++) q8[o] = 0.f;
  {
    const float* wqr = wq_w + gu * 8 * 32;  // uniform base
#pragma unroll
    for (int i = 0; i < 32; i++) {
      const float xv = xb[i * 4096 + h * 64 + w];
#pragma unroll
      for (int o = 0; o < 8; o++) q8[o] += wqr[o * 32 + i] * xv;
    }
#pragma unroll
    for (int o = 0; o < 8; o++) {
      const int oc = gu * 8 + o;
      const float s = wq_g[oc] * rsqrtf(wq_v[oc] + EPSV);
      q8[o] = (q8[o] * s + (wq_b[oc] - wq_m[oc] * s)) * 0.25f;
    }
  }

  // ---- wv[l] = q8 . k[:, l]  (49 pooled positions) ----
  float wv[49];
  {
    const float* kkb = kbuf + (size_t)b * 1568 + gu * 392;  // uniform base
#pragma unroll
    for (int l = 0; l < 49; l++) {
      float s = 0.f;
#pragma unroll
      for (int c = 0; c < 8; c++) s += q8[c] * kkb[c * 49 + l];
      wv[l] = s;
    }
  }

  // ---- relative-position-bias index bases (reference uses reversed pixel) --
  const int ph = 63 - h, pw = 63 - w;

  if (bru == 0) {
    // ================= attn1 branch (5x5 = 25) =================
    const int bih5 = ph - min(max(ph - 2, 0), 59);
    const int biw5 = pw - min(max(pw - 2, 0), 59);
    const int si5 = min(max(h - 2, 0), 59), sj5 = min(max(w - 2, 0), 59);
    float l1[25];
#pragma unroll
    for (int o = 0; o < 25; o++) {
      float s = proj_b[o];
#pragma unroll
      for (int l = 0; l < 49; l++) s += proj_w[o * 49 + l] * wv[l];
      l1[o] = s;
    }
    const float* rp1 = s_rpb1 + gu * 81 + bih5 * 9 + biw5;
#pragma unroll
    for (int ki = 0; ki < 5; ki++)
#pragma unroll
      for (int kj = 0; kj < 5; kj++) l1[ki * 5 + kj] += rp1[ki * 9 + kj];

    float mx = l1[0];
#pragma unroll
    for (int o = 1; o < 25; o++) mx = fmaxf(mx, l1[o]);
    float sum = 0.f;
#pragma unroll
    for (int o = 0; o < 25; o++) {
      const float e = __expf(l1[o] - mx);
      l1[o] = e;
      sum += e;
    }
    const float inv = 1.f / sum;

    float acc[8];
#pragma unroll
    for (int c = 0; c < 8; c++) acc[c] = 0.f;
    const float* vb = xb + gu * 8 * 4096;
#pragma unroll
    for (int i = 0; i < 5; i++) {
      const float* vr = vb + (si5 + i) * 64 + sj5;
#pragma unroll
      for (int j = 0; j < 5; j++) {
        const float a = l1[i * 5 + j];
#pragma unroll
        for (int c = 0; c < 8; c++) acc[c] += a * vr[c * 4096 + j];
      }
    }
#pragma unroll
    for (int c = 0; c < 8; c++) s_val[(gu * 8 + c) * 64 + w] = acc[c] * inv;
  } else {
    // ================= attn2 branch (7x7 = 49) =================
    const int bih7 = ph - min(max(ph - 3, 0), 57);
    const int biw7 = pw - min(max(pw - 3, 0), 57);
    const int si7 = min(max(h - 3, 0), 57), sj7 = min(max(w - 3, 0), 57);
    float l2[49];
#pragma unroll
    for (int o = 0; o < 49; o++) {
      float s = proj_b[25 + o];
#pragma unroll
      for (int l = 0; l < 49; l++) s += proj_w[(25 + o) * 49 + l] * wv[l];
      l2[o] = s;
    }
    const float* rp2 = s_rpb2 + gu * 169 + bih7 * 13 + biw7;
#pragma unroll
    for (int ki = 0; ki < 7; ki++)
#pragma unroll
      for (int kj = 0; kj < 7; kj++) l2[ki * 7 + kj] += rp2[ki * 13 + kj];

    float mx = l2[0];
#pragma unroll
    for (int o = 1; o < 49; o++) mx = fmaxf(mx, l2[o]);
    float sum = 0.f;
#pragma unroll
    for (int o = 0; o < 49; o++) {
      const float e = __expf(l2[o] - mx);
      l2[o] = e;
      sum += e;
    }
    const float inv = 1.f / sum;

    float acc[8];
#pragma unroll
    for (int c = 0; c < 8; c++) acc[c] = 0.f;
    const float* vb = xb + (32 + gu * 8) * 4096;
#pragma unroll
    for (int i = 0; i < 7; i++) {
      const float* vr = vb + (si7 + i) * 64 + sj7;
#pragma unroll
      for (int j = 0; j < 7; j++) {
        const float a = l2[i * 7 + j];
#pragma unroll
        for (int c = 0; c < 8; c++) acc[c] += a * vr[c * 4096 + j];
      }
    }
#pragma unroll
    for (int c = 0; c < 8; c++) s_val[(32 + gu * 8 + c) * 64 + w] = acc[c] * inv;
  }

  __syncthreads();

  // ================= fused final conv1x1 (64->64) + BN =================
  // 512 threads = 8 out-channel groups of 8 x 64 cols.
  {
    const int ogu = __builtin_amdgcn_readfirstlane(tid >> 6);  // 0..7
    float facc[8];
#pragma unroll
    for (int oo = 0; oo < 8; oo++) facc[oo] = 0.f;
    const float* dwr = dy_w + ogu * 8 * 64;  // uniform base
#pragma unroll
    for (int i = 0; i < 64; i++) {
      const float v = s_val[i * 64 + w];
#pragma unroll
      for (int oo = 0; oo < 8; oo++) facc[oo] += dwr[oo * 64 + i] * v;
    }
#pragma unroll
    for (int oo = 0; oo < 8; oo++) {
      const int oc = ogu * 8 + oo;
      const float sc = dy_g[oc] * rsqrtf(dy_v[oc] + EPSV);
      out[((size_t)(b * 64 + oc)) * 4096 + h * 64 + w] =
          (facc[oo] - dy_m[oc]) * sc + dy_b[oc];
    }
  }
}

// ---------------------------------------------------------------------------
extern "C" void kernel_launch(void* const* d_in, const int* in_sizes, int n_in,
                              void* d_out, int out_size, void* d_ws, size_t ws_size,
                              hipStream_t stream)
{
  const float* x      = (const float*)d_in[0];
  const float* wq_w   = (const float*)d_in[1];
  const float* wq_g   = (const float*)d_in[2];
  const float* wq_b   = (const float*)d_in[3];
  const float* wq_m   = (const float*)d_in[4];
  const float* wq_v   = (const float*)d_in[5];
  const float* wk_w   = (const float*)d_in[6];
  const float* wk_g   = (const float*)d_in[7];
  const float* wk_b   = (const float*)d_in[8];
  const float* wk_m   = (const float*)d_in[9];
  const float* wk_v   = (const float*)d_in[10];
  const float* proj_w = (const float*)d_in[11];
  const float* proj_b = (const float*)d_in[12];
  const float* rpb1   = (const float*)d_in[13];
  const float* rpb2   = (const float*)d_in[14];
  const float* dy_w   = (const float*)d_in[15];
  const float* dy_g   = (const float*)d_in[16];
  const float* dy_b   = (const float*)d_in[17];
  const float* dy_m   = (const float*)d_in[18];
  const float* dy_v   = (const float*)d_in[19];

  float* kbuf = (float*)d_ws;  // 8*32*49 floats = 50 KB

  pool_k_kernel<<<56, 256, 0, stream>>>(x, wk_w, wk_g, wk_b, wk_m, wk_v, kbuf);
  contmix_main<<<512, 512, 0, stream>>>(x, wq_w, wq_g, wq_b, wq_m, wq_v,
                                        proj_w, proj_b, rpb1, rpb2,
                                        dy_w, dy_g, dy_b, dy_m, dy_v,
                                        kbuf, (float*)d_out);
}